// Round 9
// baseline (229.105 us; speedup 1.0000x reference)
//
#include <hip/hip_runtime.h>
#include <math.h>

#define B_ 2
#define L_ 2048
#define C_ 768
#define H_ 12
#define D_ 64
#define M_ (B_ * L_)          // 4096
#define MAXLOG 4.605170185988091f   // log(100)

typedef __bf16 bf16;
typedef __bf16 bf16x4 __attribute__((ext_vector_type(4)));
typedef __bf16 bf16x8 __attribute__((ext_vector_type(8)));
typedef float  f32x4  __attribute__((ext_vector_type(4)));

// workspace element counts
#define SZ_  ((size_t)B_ * H_ * L_ * D_)   // 3,145,728 (q,k,vt, Opart-half each)
#define MC_  ((size_t)M_ * C_)             // 3,145,728 (x)
#define WQ_  ((size_t)3 * C_ * C_)         // 1,769,472 (W_qkv)
#define WP_  ((size_t)C_ * C_)             //   589,824 (W_proj)
#define BHL_ ((size_t)B_ * H_ * L_)        //    49,152

// ---------------------------------------------------------------------------
// Kernel 0: fused prep.
//   seg0: x fp32 -> bf16 (xb)      seg1: W_qkv fp32 -> bf16 (wqb)
//   seg2: W_proj fp32 -> hi/lo     seg3: zero qb..vtb (poison insurance)
//   seg4: zero tail (Opart beyond wqb + lpart)
// Opart overlays xb/wqb (dead after qkv); that part holds real data post-prep.
// ---------------------------------------------------------------------------
__global__ __launch_bounds__(256) void prep(
    const float4* __restrict__ x, const float4* __restrict__ Wq,
    const float4* __restrict__ Wp,
    bf16* __restrict__ xb, bf16* __restrict__ wqb,
    bf16* __restrict__ Wh, bf16* __restrict__ Wl,
    float4* __restrict__ zA, float4* __restrict__ zB)
{
    const int X4  = (int)(MC_ / 4);                        // 786,432
    const int W4  = (int)(WQ_ / 4);                        // 442,368
    const int S4  = (int)(WP_ / 4);                        // 147,456
    const int Z4a = (int)(3 * SZ_ * sizeof(bf16) / 16);    // 1,179,648
    // tail = Opart bytes beyond (xb+wqb) plus lpart bytes
    const int Z4b = (int)((2 * SZ_ * sizeof(float) + 2 * BHL_ * sizeof(float)
                           - (MC_ + WQ_) * sizeof(bf16)) / 16);  // 1,007,616
    const int total = X4 + W4 + S4 + Z4a + Z4b;

    const int i0 = blockIdx.x * 256 + threadIdx.x;
    const int stride = gridDim.x * 256;
    for (int i = i0; i < total; i += stride) {
        if (i < X4) {
            const float4 v = x[i];
            bf16x4 o; o[0]=(bf16)v.x; o[1]=(bf16)v.y; o[2]=(bf16)v.z; o[3]=(bf16)v.w;
            *(bf16x4*)&xb[(size_t)i * 4] = o;
        } else if (i < X4 + W4) {
            const int j = i - X4;
            const float4 v = Wq[j];
            bf16x4 o; o[0]=(bf16)v.x; o[1]=(bf16)v.y; o[2]=(bf16)v.z; o[3]=(bf16)v.w;
            *(bf16x4*)&wqb[(size_t)j * 4] = o;
        } else if (i < X4 + W4 + S4) {
            const int j = i - X4 - W4;
            const float4 v = Wp[j];
            bf16x4 h, l;
            h[0]=(bf16)v.x; l[0]=(bf16)(v.x-(float)h[0]);
            h[1]=(bf16)v.y; l[1]=(bf16)(v.y-(float)h[1]);
            h[2]=(bf16)v.z; l[2]=(bf16)(v.z-(float)h[2]);
            h[3]=(bf16)v.w; l[3]=(bf16)(v.w-(float)h[3]);
            *(bf16x4*)&Wh[(size_t)j * 4] = h;
            *(bf16x4*)&Wl[(size_t)j * 4] = l;
        } else if (i < X4 + W4 + S4 + Z4a) {
            zA[i - X4 - W4 - S4] = (float4){0.f, 0.f, 0.f, 0.f};
        } else {
            zB[i - X4 - W4 - S4 - Z4a] = (float4){0.f, 0.f, 0.f, 0.f};
        }
    }
}

// ---------------------------------------------------------------------------
// Kernel 1: QKV GEMM, bf16 MFMA, fused l2norm+scale for q/k. (unchanged R8)
// ---------------------------------------------------------------------------
__global__ __launch_bounds__(256) void qkv_mfma(
    const bf16* __restrict__ A, const bf16* __restrict__ W,
    const float* __restrict__ bias, const float* __restrict__ sml,
    bf16* __restrict__ qb, bf16* __restrict__ kb, bf16* __restrict__ vtb)
{
    __shared__ __align__(16) bf16 As[128][72];
    __shared__ __align__(16) bf16 Bs[64][72];

    const int t    = threadIdx.x;
    const int w    = t >> 6;
    const int lane = t & 63;
    const int quad = lane >> 4;
    const int c    = lane & 15;
    const int m0   = blockIdx.x * 128;
    const int n0   = blockIdx.y * 64;

    f32x4 acc[2][4];
    #pragma unroll
    for (int mt = 0; mt < 2; ++mt)
        #pragma unroll
        for (int nt = 0; nt < 4; ++nt) acc[mt][nt] = (f32x4){0.f,0.f,0.f,0.f};

    for (int kt = 0; kt < C_; kt += 64) {
        __syncthreads();
        #pragma unroll
        for (int p = 0; p < 4; ++p) {
            const int idx = t + p * 256;
            const int row = idx >> 3;
            const int cg  = (idx & 7) * 8;
            *(bf16x8*)&As[row][cg] = *(const bf16x8*)&A[(size_t)(m0 + row) * C_ + kt + cg];
        }
        #pragma unroll
        for (int p = 0; p < 2; ++p) {
            const int idx = t + p * 256;
            const int row = idx >> 3;
            const int cg  = (idx & 7) * 8;
            *(bf16x8*)&Bs[row][cg] = *(const bf16x8*)&W[(size_t)(n0 + row) * C_ + kt + cg];
        }
        __syncthreads();

        #pragma unroll
        for (int ks = 0; ks < 2; ++ks) {
            #pragma unroll
            for (int mt = 0; mt < 2; ++mt) {
                const bf16x8 a = *(const bf16x8*)&As[w * 32 + mt * 16 + c][ks * 32 + quad * 8];
                #pragma unroll
                for (int nt = 0; nt < 4; ++nt) {
                    const bf16x8 b = *(const bf16x8*)&Bs[nt * 16 + c][ks * 32 + quad * 8];
                    acc[mt][nt] = __builtin_amdgcn_mfma_f32_16x16x32_bf16(a, b, acc[mt][nt], 0, 0, 0);
                }
            }
        }
    }

    const int three = blockIdx.y / H_;
    const int h     = blockIdx.y % H_;
    const int bidx  = m0 >> 11;
    const int l0    = (m0 & (L_ - 1)) + w * 32;

    if (three < 2) {
        bf16* dst = (three == 0) ? qb : kb;
        const float scale = (three == 0) ? expf(fminf(sml[h], MAXLOG)) : 1.0f;
        #pragma unroll
        for (int mt = 0; mt < 2; ++mt) {
            float val[4][4];
            float ss[4] = {0.f, 0.f, 0.f, 0.f};
            #pragma unroll
            for (int nt = 0; nt < 4; ++nt) {
                const float bb = bias[n0 + nt * 16 + c];
                #pragma unroll
                for (int reg = 0; reg < 4; ++reg) {
                    const float v = acc[mt][nt][reg] + bb;
                    val[nt][reg] = v;
                    ss[reg] += v * v;
                }
            }
            #pragma unroll
            for (int reg = 0; reg < 4; ++reg) {
                float s = ss[reg];
                #pragma unroll
                for (int off = 1; off < 16; off <<= 1) s += __shfl_xor(s, off, 16);
                const float inv = scale / fmaxf(sqrtf(s), 1e-12f);
                const int l = l0 + mt * 16 + quad * 4 + reg;
                #pragma unroll
                for (int nt = 0; nt < 4; ++nt)
                    dst[((size_t)(bidx * H_ + h) * L_ + l) * D_ + nt * 16 + c] =
                        (bf16)(val[nt][reg] * inv);
            }
        }
    } else {
        #pragma unroll
        for (int mt = 0; mt < 2; ++mt)
            #pragma unroll
            for (int nt = 0; nt < 4; ++nt) {
                const int d = nt * 16 + c;
                const float bb = bias[n0 + d];
                const int l = l0 + mt * 16 + quad * 4;
                bf16x4 o;
                #pragma unroll
                for (int reg = 0; reg < 4; ++reg) o[reg] = (bf16)(acc[mt][nt][reg] + bb);
                *(bf16x4*)&vtb[((size_t)(bidx * H_ + h) * D_ + d) * L_ + l] = o;
            }
    }
}

// ---------------------------------------------------------------------------
// Kernel 2: flash attention v3, bf16 MFMA, fixed-offset softmax.
//   BQ=128 (wave owns 32 Q-rows = 2 m-tiles; K/V b-frags shared across them),
//   Q a-frags hoisted to registers (Qs LDS reused for P), K-split x2 over
//   blockIdx.z (fixed FMAX makes partials additive). Emits UNNORMALIZED
//   partial O [split][B,H,L,D] fp32 and partial row-sums l [split][B,H,L].
// LDS 36,864 B -> 4 blocks/CU; __launch_bounds__(256,4) caps VGPR at 128.
// ---------------------------------------------------------------------------
__global__ __launch_bounds__(256, 4) void flash_mfma(
    const bf16* __restrict__ q, const bf16* __restrict__ k,
    const bf16* __restrict__ vt, const float* __restrict__ bias,
    const float* __restrict__ sml,
    float* __restrict__ Opart, float* __restrict__ lpart)
{
    __shared__ __align__(16) bf16 QPs[128][72];   // Q in prologue, then P
    __shared__ __align__(16) bf16 Ks [64][72];
    __shared__ __align__(16) bf16 Vts[64][72];

    const int t     = threadIdx.x;
    const int w     = t >> 6;
    const int lane  = t & 63;
    const int quad  = lane >> 4;
    const int c     = lane & 15;
    const int q0    = blockIdx.x * 128;
    const int bh    = blockIdx.y;
    const int split = blockIdx.z;
    const int kt0   = split * (L_ / 2);
    const size_t base  = (size_t)bh * L_ * D_;
    const size_t vbase = (size_t)bh * D_ * L_;

    const float FMAX = expf(fminf(sml[bh % H_], MAXLOG)) + 8.0f;

    // ---- prologue: stage Q tile, hoist a-frags, free Qs for P ----
    #pragma unroll
    for (int p = 0; p < 4; ++p) {
        const int f = t + p * 256;
        const int r = f >> 3, d0 = (f & 7) * 8;
        *(bf16x8*)&QPs[r][d0] = *(const bf16x8*)&q[base + (size_t)(q0 + r) * D_ + d0];
    }
    __syncthreads();
    bf16x8 Qreg[2][2];
    #pragma unroll
    for (int mt = 0; mt < 2; ++mt)
        #pragma unroll
        for (int ks = 0; ks < 2; ++ks)
            Qreg[mt][ks] = *(const bf16x8*)&QPs[w * 32 + mt * 16 + c][ks * 32 + quad * 8];
    __syncthreads();   // all Q reads done before first P write

    float l_acc[2][4] = {};
    f32x4 O[2][4];
    #pragma unroll
    for (int mt = 0; mt < 2; ++mt)
        #pragma unroll
        for (int nt = 0; nt < 4; ++nt) O[mt][nt] = (f32x4){0.f, 0.f, 0.f, 0.f};

    for (int it = 0; it < L_ / 2; it += 64) {
        const int kt = kt0 + it;
        __syncthreads();   // prev iter's Ks/Vts/Ps reads complete
        #pragma unroll
        for (int p = 0; p < 2; ++p) {
            const int f = t + p * 256;
            const int r = f >> 3, c0 = (f & 7) * 8;
            *(bf16x8*)&Ks [r][c0] = *(const bf16x8*)&k [base  + (size_t)(kt + r) * D_ + c0];
            *(bf16x8*)&Vts[r][c0] = *(const bf16x8*)&vt[vbase + (size_t)r * L_ + kt + c0];
        }

        // S init from bias (global loads overlap the staging drain)
        f32x4 S[2][4];
        #pragma unroll
        for (int mt = 0; mt < 2; ++mt) {
            const int rb = q0 + w * 32 + mt * 16 + quad * 4;
            #pragma unroll
            for (int nt = 0; nt < 4; ++nt)
                #pragma unroll
                for (int reg = 0; reg < 4; ++reg)
                    S[mt][nt][reg] = bias[(size_t)(rb + reg) * L_ + kt + nt * 16 + c];
        }
        __syncthreads();

        // ---- S = bias + Q K^T (b-frags shared across the 2 m-tiles) ----
        #pragma unroll
        for (int ks = 0; ks < 2; ++ks) {
            bf16x8 bb[4];
            #pragma unroll
            for (int nt = 0; nt < 4; ++nt)
                bb[nt] = *(const bf16x8*)&Ks[nt * 16 + c][ks * 32 + quad * 8];
            #pragma unroll
            for (int mt = 0; mt < 2; ++mt)
                #pragma unroll
                for (int nt = 0; nt < 4; ++nt)
                    S[mt][nt] = __builtin_amdgcn_mfma_f32_16x16x32_bf16(
                        Qreg[mt][ks], bb[nt], S[mt][nt], 0, 0, 0);
        }

        // ---- p = exp(s - FMAX); per-lane row-sum; P -> LDS (over Qs) ----
        #pragma unroll
        for (int mt = 0; mt < 2; ++mt)
            #pragma unroll
            for (int nt = 0; nt < 4; ++nt)
                #pragma unroll
                for (int reg = 0; reg < 4; ++reg) {
                    const float pv = __expf(S[mt][nt][reg] - FMAX);
                    l_acc[mt][reg] += pv;
                    QPs[w * 32 + mt * 16 + quad * 4 + reg][nt * 16 + c] = (bf16)pv;
                }
        __syncthreads();

        // ---- O += P V ----
        #pragma unroll
        for (int ks = 0; ks < 2; ++ks) {
            bf16x8 bb[4];
            #pragma unroll
            for (int nt = 0; nt < 4; ++nt)
                bb[nt] = *(const bf16x8*)&Vts[nt * 16 + c][ks * 32 + quad * 8];
            #pragma unroll
            for (int mt = 0; mt < 2; ++mt) {
                const bf16x8 a = *(const bf16x8*)&QPs[w * 32 + mt * 16 + c][ks * 32 + quad * 8];
                #pragma unroll
                for (int nt = 0; nt < 4; ++nt)
                    O[mt][nt] = __builtin_amdgcn_mfma_f32_16x16x32_bf16(
                        a, bb[nt], O[mt][nt], 0, 0, 0);
            }
        }
    }

    // ---- epilogue: partial O (unnormalized) + partial l ----
    float* lp = lpart + (size_t)split * BHL_ + (size_t)bh * L_;
    float* op = Opart + (size_t)split * SZ_;
    #pragma unroll
    for (int mt = 0; mt < 2; ++mt)
        #pragma unroll
        for (int reg = 0; reg < 4; ++reg) {
            float rs = l_acc[mt][reg];
            #pragma unroll
            for (int off = 1; off < 16; off <<= 1) rs += __shfl_xor(rs, off, 16);
            const int row = q0 + w * 32 + mt * 16 + quad * 4 + reg;
            if (c == 0) lp[row] = rs;
            const size_t ob = ((size_t)bh * L_ + row) * D_;
            #pragma unroll
            for (int nt = 0; nt < 4; ++nt)
                op[ob + nt * 16 + c] = O[mt][nt][reg];
        }
}

// ---------------------------------------------------------------------------
// Kernel 3: projection GEMM with FUSED combine: A-staging reads the two
// Opart halves + l partials, normalizes ((O1+O2)/(l1+l2)), hi/lo-splits.
// W pre-split. BM=128, BN=64, BK=64 (one head per k-tile: h = kt/64).
// ---------------------------------------------------------------------------
__global__ __launch_bounds__(256) void proj_mfma(
    const float* __restrict__ Op0, const float* __restrict__ Op1,
    const float* __restrict__ lp0, const float* __restrict__ lp1,
    const bf16* __restrict__ Whg, const bf16* __restrict__ Wlg,
    const float* __restrict__ bias, float* __restrict__ outp)
{
    __shared__ __align__(16) bf16 Ah[128][72];
    __shared__ __align__(16) bf16 Al[128][72];
    __shared__ __align__(16) bf16 Bh[64][72];
    __shared__ __align__(16) bf16 Bl[64][72];

    const int t    = threadIdx.x;
    const int w    = t >> 6;
    const int lane = t & 63;
    const int quad = lane >> 4;
    const int c    = lane & 15;
    const int m0   = blockIdx.x * 128;
    const int n0   = blockIdx.y * 64;

    f32x4 acc[2][4];
    #pragma unroll
    for (int mt = 0; mt < 2; ++mt)
        #pragma unroll
        for (int nt = 0; nt < 4; ++nt) acc[mt][nt] = (f32x4){0.f,0.f,0.f,0.f};

    for (int kt = 0; kt < C_; kt += 64) {
        const int h = kt >> 6;          // k-tile spans exactly one head
        __syncthreads();
        // ---- A staging: combine + normalize + hi/lo split ----
        #pragma unroll
        for (int p = 0; p < 4; ++p) {
            const int idx = t + p * 256;          // 0..1023
            const int rl  = idx >> 3;             // 0..127
            const int cg  = (idx & 7) * 8;        // d-offset 0..56
            const int row = m0 + rl;
            const int bi  = row >> 11;
            const int l   = row & (L_ - 1);
            const size_t bhrow = ((size_t)(bi * H_ + h) * L_ + l);
            const float linv = 1.0f / (lp0[bhrow] + lp1[bhrow]);
            const float* a0 = &Op0[bhrow * D_ + cg];
            const float* a1 = &Op1[bhrow * D_ + cg];
            const float4 u0 = *(const float4*)a0;
            const float4 u1 = *(const float4*)(a0 + 4);
            const float4 v0 = *(const float4*)a1;
            const float4 v1 = *(const float4*)(a1 + 4);
            float vals[8];
            vals[0] = (u0.x + v0.x) * linv; vals[1] = (u0.y + v0.y) * linv;
            vals[2] = (u0.z + v0.z) * linv; vals[3] = (u0.w + v0.w) * linv;
            vals[4] = (u1.x + v1.x) * linv; vals[5] = (u1.y + v1.y) * linv;
            vals[6] = (u1.z + v1.z) * linv; vals[7] = (u1.w + v1.w) * linv;
            bf16x8 hv, lv;
            #pragma unroll
            for (int j = 0; j < 8; ++j) {
                hv[j] = (bf16)vals[j];
                lv[j] = (bf16)(vals[j] - (float)hv[j]);
            }
            *(bf16x8*)&Ah[rl][cg] = hv;
            *(bf16x8*)&Al[rl][cg] = lv;
        }
        // ---- B staging: pre-split W (pure b128 copies) ----
        #pragma unroll
        for (int p = 0; p < 2; ++p) {
            const int idx = t + p * 256;
            const int row = idx >> 3;             // 0..63
            const int cg  = (idx & 7) * 8;
            *(bf16x8*)&Bh[row][cg] = *(const bf16x8*)&Whg[(size_t)(n0 + row) * C_ + kt + cg];
            *(bf16x8*)&Bl[row][cg] = *(const bf16x8*)&Wlg[(size_t)(n0 + row) * C_ + kt + cg];
        }
        __syncthreads();

        #pragma unroll
        for (int ks = 0; ks < 2; ++ks) {
            #pragma unroll
            for (int mt = 0; mt < 2; ++mt) {
                const bf16x8 ah = *(const bf16x8*)&Ah[w * 32 + mt * 16 + c][ks * 32 + quad * 8];
                const bf16x8 al = *(const bf16x8*)&Al[w * 32 + mt * 16 + c][ks * 32 + quad * 8];
                #pragma unroll
                for (int nt = 0; nt < 4; ++nt) {
                    const bf16x8 bh = *(const bf16x8*)&Bh[nt * 16 + c][ks * 32 + quad * 8];
                    const bf16x8 bl = *(const bf16x8*)&Bl[nt * 16 + c][ks * 32 + quad * 8];
                    acc[mt][nt] = __builtin_amdgcn_mfma_f32_16x16x32_bf16(ah, bh, acc[mt][nt], 0, 0, 0);
                    acc[mt][nt] = __builtin_amdgcn_mfma_f32_16x16x32_bf16(ah, bl, acc[mt][nt], 0, 0, 0);
                    acc[mt][nt] = __builtin_amdgcn_mfma_f32_16x16x32_bf16(al, bh, acc[mt][nt], 0, 0, 0);
                }
            }
        }
    }

    #pragma unroll
    for (int mt = 0; mt < 2; ++mt)
        #pragma unroll
        for (int nt = 0; nt < 4; ++nt) {
            const int col = n0 + nt * 16 + c;
            const float bb = bias[col];
            #pragma unroll
            for (int reg = 0; reg < 4; ++reg) {
                const int row = m0 + w * 32 + mt * 16 + quad * 4 + reg;
                outp[(size_t)row * C_ + col] = acc[mt][nt][reg] + bb;
            }
        }
}

// ---------------------------------------------------------------------------
extern "C" void kernel_launch(void* const* d_in, const int* in_sizes, int n_in,
                              void* d_out, int out_size, void* d_ws, size_t ws_size,
                              hipStream_t stream)
{
    const float* x         = (const float*)d_in[0];
    const float* attn_bias = (const float*)d_in[1];
    const float* W_qkv     = (const float*)d_in[2];
    const float* b_qkv     = (const float*)d_in[3];
    const float* sml       = (const float*)d_in[4];
    const float* W_proj    = (const float*)d_in[5];
    const float* b_proj    = (const float*)d_in[6];
    float* out = (float*)d_out;

    // ws layout (bytes):
    //   qb kb vtb            : 3*SZ bf16      (zeroed by prep seg3)
    //   Wh Wl                : 2*WP bf16      (prep-written)
    //   xb                   : MC bf16        (prep-written; Opart overlays)
    //   wqb                  : WQ bf16        (prep-written; Opart overlays)
    //   Opart tail + lpart   : fresh          (zeroed by prep seg4)
    bf16* qb  = (bf16*)d_ws;
    bf16* kb  = qb  + SZ_;
    bf16* vtb = kb  + SZ_;
    bf16* Wh  = vtb + SZ_;
    bf16* Wl  = Wh  + WP_;
    bf16* xb  = Wl  + WP_;
    bf16* wqb = xb  + MC_;
    float* Op0 = (float*)xb;                 // overlay: 2*SZ floats total
    float* Op1 = Op0 + SZ_;
    float* lp0 = Op0 + 2 * SZ_;              // 2*BHL floats
    float* lp1 = lp0 + BHL_;
    float4* zA = (float4*)qb;                        // zero: qb..vtb
    float4* zB = (float4*)(wqb + WQ_);               // zero: Opart tail + lpart

    // 0) fused prep
    prep<<<2048, 256, 0, stream>>>(
        (const float4*)x, (const float4*)W_qkv, (const float4*)W_proj,
        xb, wqb, Wh, Wl, zA, zB);

    // 1) QKV GEMM (bf16 MFMA, fused l2norm+scale)
    qkv_mfma<<<dim3(M_ / 128, (3 * C_) / 64), 256, 0, stream>>>(
        xb, wqb, b_qkv, sml, qb, kb, vtb);

    // 2) flash attention v3 (BQ=128, K-split x2) -> partial O/l
    flash_mfma<<<dim3(L_ / 128, B_ * H_, 2), 256, 0, stream>>>(
        qb, kb, vtb, attn_bias, sml, Op0, lp0);

    // 3) projection GEMM with fused combine/normalize/split
    proj_mfma<<<dim3(M_ / 128, C_ / 64), 256, 0, stream>>>(
        Op0, Op1, lp0, lp1, Wh, Wl, b_proj, out);
}